// Round 8
// baseline (562.587 us; speedup 1.0000x reference)
//
#include <hip/hip_runtime.h>
#include <hip/hip_bf16.h>

#define DD 128
#define NBLK 256     // blocks for hist/place passes
#define MAXBUK 1024  // max dst-buckets (256 nodes each)
#define CAP2 12288   // max edges per bucket for LDS sort staging

typedef __attribute__((ext_vector_type(8))) short bf16x8;
typedef __attribute__((ext_vector_type(4))) float f32x4;
typedef unsigned int uint32;

__device__ __forceinline__ unsigned short f2b(float f) {
  __hip_bfloat16 h = __float2bfloat16(f);
  unsigned short u;
  __builtin_memcpy(&u, &h, 2);
  return u;
}
__device__ __forceinline__ float b2f_lo(uint32 v) { return __uint_as_float(v << 16); }
__device__ __forceinline__ float b2f_hi(uint32 v) { return __uint_as_float(v & 0xffff0000u); }

__device__ __forceinline__ void acc8(float* acc, uint4 h, float w) {
  acc[0] = fmaf(w, b2f_lo(h.x), acc[0]);
  acc[1] = fmaf(w, b2f_hi(h.x), acc[1]);
  acc[2] = fmaf(w, b2f_lo(h.y), acc[2]);
  acc[3] = fmaf(w, b2f_hi(h.y), acc[3]);
  acc[4] = fmaf(w, b2f_lo(h.z), acc[4]);
  acc[5] = fmaf(w, b2f_hi(h.z), acc[5]);
  acc[6] = fmaf(w, b2f_lo(h.w), acc[6]);
  acc[7] = fmaf(w, b2f_hi(h.w), acc[7]);
}

// per-block int64-vs-int32 detection: hi-words of first 64 src entries all zero <=> int64
__device__ __forceinline__ bool detect_i64(const int* e, int E) {
  int lane = threadIdx.x & 63;
  int samples = E < 64 ? E : 64;
  int v = (lane < samples) ? e[2 * lane + 1] : 0;
  return __ballot(v != 0) == 0ULL;
}

// ---------------- per-block bucket histogram ----------------
__global__ __launch_bounds__(256) void k_hist(const void* __restrict__ eptr, int E,
                                              int* __restrict__ histT, int nbuk) {
  __shared__ int hist[MAXBUK];
  int t = threadIdx.x, blk = blockIdx.x;
  bool f = detect_i64((const int*)eptr, E);
  for (int b = t; b < nbuk; b += 256) hist[b] = 0;
  __syncthreads();
  int chunk = (E + NBLK - 1) / NBLK;
  int i0 = blk * chunk, i1 = min(E, i0 + chunk);
  for (int i = i0 + t; i < i1; i += 256) {
    int dst = f ? (int)((const long long*)eptr)[E + i] : ((const int*)eptr)[E + i];
    atomicAdd(&hist[dst >> 8], 1);
  }
  __syncthreads();
  for (int b = t; b < nbuk; b += 256) histT[b * NBLK + blk] = hist[b];
}

// ---------------- single-block: bucket totals, bucket base scan, per-block offsets ----------------
__global__ __launch_bounds__(1024) void k_bktscan(const int* __restrict__ histT,
                                                  int* __restrict__ offs,
                                                  int* __restrict__ bucketBase,
                                                  int nbuk, int E) {
  __shared__ int tot[MAXBUK];
  int t = threadIdx.x, lane = t & 63, wv = t >> 6;  // 16 waves
  for (int b = t; b < MAXBUK; b += 1024) tot[b] = 0;
  __syncthreads();
  for (int b = wv; b < nbuk; b += 16) {
    const int4 vv = *(const int4*)(histT + b * NBLK + lane * 4);
    int lsum = vv.x + vv.y + vv.z + vv.w;
    int s = lsum;
#pragma unroll
    for (int o = 1; o < 64; o <<= 1) {
      int u = __shfl_up(s, o);
      if (lane >= o) s += u;
    }
    if (lane == 63) tot[b] = s;
  }
  __syncthreads();
  for (int o = 1; o < MAXBUK; o <<= 1) {
    int u = (t >= o) ? tot[t - o] : 0;
    __syncthreads();
    tot[t] += u;
    __syncthreads();
  }
  for (int b = wv; b < nbuk; b += 16) {
    int idx = b * NBLK + lane * 4;
    const int4 vv = *(const int4*)(histT + idx);
    int lsum = vv.x + vv.y + vv.z + vv.w;
    int s = lsum;
#pragma unroll
    for (int o = 1; o < 64; o <<= 1) {
      int u = __shfl_up(s, o);
      if (lane >= o) s += u;
    }
    int tb = __shfl(s, 63);
    int bbase = tot[b] - tb;
    int excl = bbase + s - lsum;
    offs[idx] = excl;
    offs[idx + 1] = excl + vv.x;
    offs[idx + 2] = excl + vv.x + vv.y;
    offs[idx + 3] = excl + vv.x + vv.y + vv.z;
    if (lane == 0) bucketBase[b] = bbase;
  }
  if (t == 0) bucketBase[nbuk] = E;
}

// ---------------- place edges into bucket regions (block-contiguous runs) ----------------
__global__ __launch_bounds__(256) void k_place(const void* __restrict__ eptr, int E,
                                               const int* __restrict__ offs,
                                               int* __restrict__ ebuk, int nbuk) {
  __shared__ int cur[MAXBUK];
  int t = threadIdx.x, blk = blockIdx.x;
  bool f = detect_i64((const int*)eptr, E);
  for (int b = t; b < nbuk; b += 256) cur[b] = offs[b * NBLK + blk];
  __syncthreads();
  int chunk = (E + NBLK - 1) / NBLK;
  int i0 = blk * chunk, i1 = min(E, i0 + chunk);
  for (int i = i0 + t; i < i1; i += 256) {
    int src, dst;
    if (f) {
      src = (int)((const long long*)eptr)[i];
      dst = (int)((const long long*)eptr)[E + i];
    } else {
      src = ((const int*)eptr)[i];
      dst = ((const int*)eptr)[E + i];
    }
    int pos = atomicAdd(&cur[dst >> 8], 1);
    ebuk[pos] = (src << 8) | (dst & 255);
  }
}

// ---------------- per-bucket: degree count -> rp + dinv + LDS counting sort -> csrc ----------------
__global__ __launch_bounds__(256) void k_bsort2(const int* __restrict__ ebuk,
                                                const int* __restrict__ bucketBase,
                                                int* __restrict__ rp, float* __restrict__ dinv,
                                                int* __restrict__ csrc, int n) {
  __shared__ int cnt[256];
  __shared__ int wss[4];
  __shared__ int outb[CAP2];
  int b = blockIdx.x, t = threadIdx.x, lane = t & 63, wv = t >> 6;
  int v0 = b << 8;
  int v1 = min(v0 + 256, n);
  int nn = v1 - v0;
  int base = bucketBase[b];
  int total = bucketBase[b + 1] - base;
  cnt[t] = 0;
  __syncthreads();
  for (int i = t; i < total; i += 256) atomicAdd(&cnt[ebuk[base + i] & 255], 1);
  __syncthreads();
  int v = cnt[t];
  int incl = v;
#pragma unroll
  for (int o = 1; o < 64; o <<= 1) {
    int u = __shfl_up(incl, o);
    if (lane >= o) incl += u;
  }
  if (lane == 63) wss[wv] = incl;
  __syncthreads();
  int woff = 0;
  for (int k = 0; k < wv; ++k) woff += wss[k];
  int excl = woff + incl - v;
  if (t < nn) {
    rp[v0 + t] = base + excl;
    dinv[v0 + t] = rsqrtf((float)v + 1.0f);
  }
  if (t == 255) rp[v1] = base + excl + v;
  __syncthreads();
  cnt[t] = excl;
  __syncthreads();
  if (total <= CAP2) {
    for (int i = t; i < total; i += 256) {
      int e = ebuk[base + i];
      int slot = atomicAdd(&cnt[e & 255], 1);
      outb[slot] = e >> 8;
    }
    __syncthreads();
    for (int i = t; i < total; i += 256) csrc[base + i] = outb[i];
  } else {
    for (int i = t; i < total; i += 256) {
      int e = ebuk[base + i];
      int slot = atomicAdd(&cnt[e & 255], 1);
      csrc[base + slot] = e >> 8;
    }
  }
}

// ---------------- fused: x -> bf16 + column stats (blocks 0..1023), W prep (1024..1151) ----------------
__global__ __launch_bounds__(256) void k_cvtw(const float4* __restrict__ x,
                                              ushort4* __restrict__ xb, int n4,
                                              float* __restrict__ part,
                                              const float* __restrict__ W1,
                                              const float* __restrict__ W2,
                                              unsigned short* __restrict__ wimg) {
  __shared__ float sh[256][8];
  int t = threadIdx.x;
  int bid = blockIdx.x;
  if (bid >= 1024) {
    int i = (bid - 1024) * 256 + t;  // 0..32767
    if (i < 32768) {
      int wsel = i >> 14;
      int j = i & 16383;
      int k = j >> 7, col = j & 127;
      float v = (wsel ? W2 : W1)[j];
      int chunk = (k >> 3) ^ (col & 7);
      wimg[wsel * 16384 + col * 128 + chunk * 8 + (k & 7)] = f2b(v);
    }
    return;
  }
  float s[4] = {0, 0, 0, 0}, q[4] = {0, 0, 0, 0};
  for (int i = bid * 256 + t; i < n4; i += 1024 * 256) {
    float4 a = x[i];
    ushort4 o;
    o.x = f2b(a.x); o.y = f2b(a.y); o.z = f2b(a.z); o.w = f2b(a.w);
    xb[i] = o;
    s[0] += a.x; s[1] += a.y; s[2] += a.z; s[3] += a.w;
    q[0] = fmaf(a.x, a.x, q[0]); q[1] = fmaf(a.y, a.y, q[1]);
    q[2] = fmaf(a.z, a.z, q[2]); q[3] = fmaf(a.w, a.w, q[3]);
  }
#pragma unroll
  for (int j = 0; j < 4; ++j) { sh[t][j] = s[j]; sh[t][4 + j] = q[j]; }
  __syncthreads();
  if (t < 32) {
#pragma unroll
    for (int g = 1; g < 8; ++g)
#pragma unroll
      for (int j = 0; j < 4; ++j) {
        s[j] += sh[g * 32 + t][j];
        q[j] += sh[g * 32 + t][4 + j];
      }
    float* pp = part + (size_t)(bid & 63) * 768;
#pragma unroll
    for (int j = 0; j < 4; ++j) {
      atomicAdd(&pp[(t * 4 + j) * 2], s[j]);
      atomicAdd(&pp[(t * 4 + j) * 2 + 1], q[j]);
    }
  }
}

// ---------------- MFMA GEMM: H = bf16((A @ W) * dinv[row]) ----------------
__global__ __launch_bounds__(256) void k_gemm(const unsigned short* __restrict__ Ab,
                                              const unsigned short* __restrict__ Wimg,
                                              const float* __restrict__ dinv,
                                              unsigned short* __restrict__ H, int n) {
  __shared__ __align__(16) unsigned short Wl[16384];
  int t = threadIdx.x, lane = t & 63, w = t >> 6;
#pragma unroll
  for (int i = t; i < 2048; i += 256) ((int4*)Wl)[i] = ((const int4*)Wimg)[i];
  __syncthreads();
  int rowBase = blockIdx.x * 128 + w * 32;
  int r16 = lane & 15, half = lane >> 4;
  f32x4 acc[2][8];
#pragma unroll
  for (int m = 0; m < 2; ++m)
#pragma unroll
    for (int nn = 0; nn < 8; ++nn) acc[m][nn] = (f32x4){0.f, 0.f, 0.f, 0.f};
#pragma unroll
  for (int ks = 0; ks < 4; ++ks) {
    bf16x8 a[2];
#pragma unroll
    for (int m = 0; m < 2; ++m) {
      int r = rowBase + m * 16 + r16;
      if (r >= n) r = n - 1;
      a[m] = *(const bf16x8*)(Ab + (size_t)r * DD + ks * 32 + half * 8);
    }
#pragma unroll
    for (int nn = 0; nn < 8; ++nn) {
      int col = nn * 16 + r16;
      int chunk = (ks * 4 + half) ^ (col & 7);
      bf16x8 b = *(const bf16x8*)(Wl + col * 128 + chunk * 8);
      acc[0][nn] = __builtin_amdgcn_mfma_f32_16x16x32_bf16(a[0], b, acc[0][nn], 0, 0, 0);
      acc[1][nn] = __builtin_amdgcn_mfma_f32_16x16x32_bf16(a[1], b, acc[1][nn], 0, 0, 0);
    }
  }
#pragma unroll
  for (int m = 0; m < 2; ++m) {
    int rb = rowBase + m * 16 + half * 4;
    float dv[4];
#pragma unroll
    for (int i = 0; i < 4; ++i) dv[i] = (rb + i < n) ? dinv[rb + i] : 0.f;
#pragma unroll
    for (int nn = 0; nn < 8; ++nn) {
      int col = nn * 16 + r16;
#pragma unroll
      for (int i = 0; i < 4; ++i) {
        int r = rb + i;
        if (r < n) H[(size_t)r * DD + col] = f2b(acc[m][nn][i] * dv[i]);
      }
    }
  }
}

// ---------------- aggregation: XCD-sliced columns (slice = blockIdx & 7 -> L2-resident) ----------------
// block: 4 waves x 8 nodes, 16 cols (32B) per block; lane: node=(lane>>4), eidx=(lane>>1)&7, seg=lane&1
__global__ __launch_bounds__(256) void k_agg(const unsigned short* __restrict__ hs,
                                             const float* __restrict__ dinv,
                                             const float* __restrict__ b,
                                             const int* __restrict__ rp,
                                             const int* __restrict__ csrc,
                                             unsigned short* __restrict__ y, int n,
                                             float* __restrict__ part, int cb) {
  __shared__ float sh_s[4][2][8];
  __shared__ float sh_q[4][2][8];
  int slice = blockIdx.x & 7;
  int nb = blockIdx.x >> 3;
  int t = threadIdx.x, wid = t >> 6, lane = t & 63;
  int nodeIdx = lane >> 4;      // 0..3
  int eidx = (lane >> 1) & 7;   // 0..7
  int seg = lane & 1;           // 0..1
  int gbase = nodeIdx << 4;
  int l16 = lane & 15;
  int vA = nb * 32 + wid * 8 + nodeIdx;
  int vB = vA + 4;
  bool okA = vA < n, okB = vB < n;
  int a0 = 0, b0 = 0, a1 = 0, b1 = 0;
  if (okA) { a0 = rp[vA]; b0 = rp[vA + 1]; }
  if (okB) { a1 = rp[vB]; b1 = rp[vB + 1]; }
  const uint4* H4 = (const uint4*)hs;  // row = 16 uint4
  int so = slice * 2 + seg;            // uint4 offset within row
  float accA[8], accB[8];
#pragma unroll
  for (int j = 0; j < 8; ++j) { accA[j] = 0.f; accB[j] = 0.f; }
  int ebA = a0, ebB = a1;
  while (ebA < b0 || ebB < b1) {
    int ulA = (ebA + l16 < b0) ? csrc[ebA + l16] : 0;
    int ulB = (ebB + l16 < b1) ? csrc[ebB + l16] : 0;
    int uA0 = __shfl(ulA, gbase + eidx);
    int uA1 = __shfl(ulA, gbase + 8 + eidx);
    int uB0 = __shfl(ulB, gbase + eidx);
    int uB1 = __shfl(ulB, gbase + 8 + eidx);
    float wA0 = (ebA + eidx < b0) ? 1.f : 0.f;
    float wA1 = (ebA + 8 + eidx < b0) ? 1.f : 0.f;
    float wB0 = (ebB + eidx < b1) ? 1.f : 0.f;
    float wB1 = (ebB + 8 + eidx < b1) ? 1.f : 0.f;
    uint4 hA0 = H4[(size_t)uA0 * 16 + so];
    uint4 hA1 = H4[(size_t)uA1 * 16 + so];
    uint4 hB0 = H4[(size_t)uB0 * 16 + so];
    uint4 hB1 = H4[(size_t)uB1 * 16 + so];
    acc8(accA, hA0, wA0);
    acc8(accA, hA1, wA1);
    acc8(accB, hB0, wB0);
    acc8(accB, hB1, wB1);
    ebA += 16;
    ebB += 16;
  }
  // butterfly over eidx bits (lane bits 1..3): every lane gets the per-(node,seg) total
#pragma unroll
  for (int j = 0; j < 8; ++j) {
    accA[j] += __shfl_xor(accA[j], 2);
    accA[j] += __shfl_xor(accA[j], 4);
    accA[j] += __shfl_xor(accA[j], 8);
    accB[j] += __shfl_xor(accB[j], 2);
    accB[j] += __shfl_xor(accB[j], 4);
    accB[j] += __shfl_xor(accB[j], 8);
  }
  float4 bb0 = ((const float4*)b)[slice * 4 + seg * 2];
  float4 bb1 = ((const float4*)b)[slice * 4 + seg * 2 + 1];
  float bv[8] = {bb0.x, bb0.y, bb0.z, bb0.w, bb1.x, bb1.y, bb1.z, bb1.w};
  float oA[8], oB[8];
  if (okA) {
    uint4 sfv = H4[(size_t)vA * 16 + so];
    float sf[8] = {b2f_lo(sfv.x), b2f_hi(sfv.x), b2f_lo(sfv.y), b2f_hi(sfv.y),
                   b2f_lo(sfv.z), b2f_hi(sfv.z), b2f_lo(sfv.w), b2f_hi(sfv.w)};
    float dv = dinv[vA];
#pragma unroll
    for (int j = 0; j < 8; ++j) oA[j] = fmaxf(fmaf(dv, accA[j] + sf[j], bv[j]), 0.f);
    if (eidx == 0) {
      uint4 ov;
      ov.x = (uint32)f2b(oA[0]) | ((uint32)f2b(oA[1]) << 16);
      ov.y = (uint32)f2b(oA[2]) | ((uint32)f2b(oA[3]) << 16);
      ov.z = (uint32)f2b(oA[4]) | ((uint32)f2b(oA[5]) << 16);
      ov.w = (uint32)f2b(oA[6]) | ((uint32)f2b(oA[7]) << 16);
      ((uint4*)y)[(size_t)vA * 16 + so] = ov;
    }
  } else {
#pragma unroll
    for (int j = 0; j < 8; ++j) oA[j] = 0.f;
  }
  if (okB) {
    uint4 sfv = H4[(size_t)vB * 16 + so];
    float sf[8] = {b2f_lo(sfv.x), b2f_hi(sfv.x), b2f_lo(sfv.y), b2f_hi(sfv.y),
                   b2f_lo(sfv.z), b2f_hi(sfv.z), b2f_lo(sfv.w), b2f_hi(sfv.w)};
    float dv = dinv[vB];
#pragma unroll
    for (int j = 0; j < 8; ++j) oB[j] = fmaxf(fmaf(dv, accB[j] + sf[j], bv[j]), 0.f);
    if (eidx == 0) {
      uint4 ov;
      ov.x = (uint32)f2b(oB[0]) | ((uint32)f2b(oB[1]) << 16);
      ov.y = (uint32)f2b(oB[2]) | ((uint32)f2b(oB[3]) << 16);
      ov.z = (uint32)f2b(oB[4]) | ((uint32)f2b(oB[5]) << 16);
      ov.w = (uint32)f2b(oB[6]) | ((uint32)f2b(oB[7]) << 16);
      ((uint4*)y)[(size_t)vB * 16 + so] = ov;
    }
  } else {
#pragma unroll
    for (int j = 0; j < 8; ++j) oB[j] = 0.f;
  }
  // stats: sum over the wave's 8 nodes (butterfly over node bits 4,5; dups in eidx are parallel copies)
  float s[8], q[8];
#pragma unroll
  for (int j = 0; j < 8; ++j) {
    s[j] = oA[j] + oB[j];
    q[j] = oA[j] * oA[j] + oB[j] * oB[j];
  }
#pragma unroll
  for (int j = 0; j < 8; ++j) {
    s[j] += __shfl_xor(s[j], 16);
    s[j] += __shfl_xor(s[j], 32);
    q[j] += __shfl_xor(q[j], 16);
    q[j] += __shfl_xor(q[j], 32);
  }
  if (lane < 2) {
#pragma unroll
    for (int j = 0; j < 8; ++j) {
      sh_s[wid][lane][j] = s[j];
      sh_q[wid][lane][j] = q[j];
    }
  }
  __syncthreads();
  if (t < 16) {
    int sg = t >> 3, j = t & 7;
    float ss = sh_s[0][sg][j] + sh_s[1][sg][j] + sh_s[2][sg][j] + sh_s[3][sg][j];
    float qq = sh_q[0][sg][j] + sh_q[1][sg][j] + sh_q[2][sg][j] + sh_q[3][sg][j];
    float* pp = part + (size_t)(blockIdx.x & 63) * 768;
    atomicAdd(&pp[(cb + slice * 16 + t) * 2], ss);
    atomicAdd(&pp[(cb + slice * 16 + t) * 2 + 1], qq);
  }
}

// ---------------- BN fold: reduce partials, compute scale/shift + folded bias ----------------
__global__ void k_fold_a(const float* __restrict__ part, const float* __restrict__ gamma,
                         const float* __restrict__ beta, const float* __restrict__ Wo,
                         const float* __restrict__ bo, float* __restrict__ aS,
                         float* __restrict__ boP, int n) {
  __shared__ float cSh[384];
  int t = threadIdx.x;  // 0..383
  float s = 0.f, q = 0.f;
  for (int r = 0; r < 64; ++r) {
    s += part[r * 768 + t * 2];
    q += part[r * 768 + t * 2 + 1];
  }
  float inv_n = 1.0f / (float)n;
  float mu = s * inv_n;
  float var = q * inv_n - mu * mu;
  float a = gamma[t] * rsqrtf(var + 1e-5f);
  aS[t] = a;
  cSh[t] = beta[t] - mu * a;
  __syncthreads();
  if (t < DD) {
    float sb = bo[t];
    for (int k = 0; k < 384; ++k) sb = fmaf(cSh[k], Wo[k * DD + t], sb);
    boP[t] = sb;
  }
}

// ---------------- WoP image (bf16, pre-swizzled) ----------------
__global__ void k_foldw(const float* __restrict__ aS, const float* __restrict__ Wo,
                        unsigned short* __restrict__ wopimg) {
  int i = blockIdx.x * 256 + threadIdx.x;  // 0..49151
  if (i >= 49152) return;
  int krow = i >> 7, col = i & 127;
  float v = aS[krow] * Wo[i];
  int p = krow >> 7, kk = krow & 127;
  int chunk = (kk >> 3) ^ (col & 7);
  wopimg[p * 16384 + col * 128 + chunk * 8 + (kk & 7)] = f2b(v);
}

// ---------------- final MFMA GEMM: out = [xb|y1|y2] @ WoP + boP (f32 out) ----------------
__global__ __launch_bounds__(256) void k_gemm_out(const unsigned short* __restrict__ xb,
                                                  const unsigned short* __restrict__ y1,
                                                  const unsigned short* __restrict__ y2,
                                                  const unsigned short* __restrict__ Wimg3,
                                                  const float* __restrict__ boP,
                                                  float* __restrict__ out, int n) {
  __shared__ __align__(16) unsigned short Wl[16384];
  int t = threadIdx.x, lane = t & 63, w = t >> 6;
  int rowBase = blockIdx.x * 128 + w * 32;
  int r16 = lane & 15, half = lane >> 4;
  f32x4 acc[2][8];
#pragma unroll
  for (int m = 0; m < 2; ++m)
#pragma unroll
    for (int nn = 0; nn < 8; ++nn) acc[m][nn] = (f32x4){0.f, 0.f, 0.f, 0.f};
  for (int p = 0; p < 3; ++p) {
    const unsigned short* Ab = (p == 0) ? xb : (p == 1) ? y1 : y2;
    __syncthreads();
#pragma unroll
    for (int i = t; i < 2048; i += 256) ((int4*)Wl)[i] = ((const int4*)(Wimg3 + p * 16384))[i];
    __syncthreads();
#pragma unroll
    for (int ks = 0; ks < 4; ++ks) {
      bf16x8 a[2];
#pragma unroll
      for (int m = 0; m < 2; ++m) {
        int r = rowBase + m * 16 + r16;
        if (r >= n) r = n - 1;
        a[m] = *(const bf16x8*)(Ab + (size_t)r * DD + ks * 32 + half * 8);
      }
#pragma unroll
      for (int nn = 0; nn < 8; ++nn) {
        int col = nn * 16 + r16;
        int chunk = (ks * 4 + half) ^ (col & 7);
        bf16x8 b = *(const bf16x8*)(Wl + col * 128 + chunk * 8);
        acc[0][nn] = __builtin_amdgcn_mfma_f32_16x16x32_bf16(a[0], b, acc[0][nn], 0, 0, 0);
        acc[1][nn] = __builtin_amdgcn_mfma_f32_16x16x32_bf16(a[1], b, acc[1][nn], 0, 0, 0);
      }
    }
  }
#pragma unroll
  for (int m = 0; m < 2; ++m) {
    int rb = rowBase + m * 16 + half * 4;
#pragma unroll
    for (int nn = 0; nn < 8; ++nn) {
      int col = nn * 16 + r16;
      float bb = boP[col];
#pragma unroll
      for (int i = 0; i < 4; ++i) {
        int r = rb + i;
        if (r < n) out[(size_t)r * DD + col] = acc[m][nn][i] + bb;
      }
    }
  }
}

extern "C" void kernel_launch(void* const* d_in, const int* in_sizes, int n_in,
                              void* d_out, int out_size, void* d_ws, size_t ws_size,
                              hipStream_t stream) {
  const float* x = (const float*)d_in[0];
  const void* ept = d_in[1];
  const float* W1 = (const float*)d_in[2];
  const float* b1 = (const float*)d_in[3];
  const float* W2 = (const float*)d_in[4];
  const float* b2 = (const float*)d_in[5];
  const float* gamma = (const float*)d_in[6];
  const float* beta = (const float*)d_in[7];
  const float* Wo = (const float*)d_in[8];
  const float* bo = (const float*)d_in[9];
  float* out = (float*)d_out;
  int N = in_sizes[0] / DD;
  int E = in_sizes[1] / 2;
  int nbuk = (N + 255) >> 8;  // must be <= MAXBUK (N <= 262144)

  char* w = (char*)d_ws;
  size_t off = 0;
  auto alloc = [&](size_t bytes) {
    void* p = w + off;
    off = (off + bytes + 255) & ~(size_t)255;
    return p;
  };
  float* dinv = (float*)alloc((size_t)N * 4);
  int* rp = (int*)alloc((size_t)(N + 1) * 4);
  int* csrc = (int*)alloc((size_t)E * 4);
  int* ebuk = (int*)alloc((size_t)E * 4);
  int* histT = (int*)alloc((size_t)MAXBUK * NBLK * 4);
  int* offs = (int*)alloc((size_t)MAXBUK * NBLK * 4);
  int* bucketBase = (int*)alloc((size_t)(MAXBUK + 1) * 4);
  unsigned short* xb = (unsigned short*)alloc((size_t)N * DD * 2);
  unsigned short* h = (unsigned short*)alloc((size_t)N * DD * 2);
  unsigned short* y1 = (unsigned short*)alloc((size_t)N * DD * 2);
  unsigned short* y2 = (unsigned short*)alloc((size_t)N * DD * 2);
  unsigned short* wimg = (unsigned short*)alloc(32768 * 2);
  unsigned short* wopimg = (unsigned short*)alloc(49152 * 2);
  float* part = (float*)alloc((size_t)64 * 768 * 4);
  float* aS = (float*)alloc(384 * 4);
  float* boP = (float*)alloc(DD * 4);

  hipMemsetAsync(part, 0, (size_t)64 * 768 * 4, stream);

  // CSR construction (atomic-free, bucketized)
  k_hist<<<NBLK, 256, 0, stream>>>(ept, E, histT, nbuk);
  k_bktscan<<<1, 1024, 0, stream>>>(histT, offs, bucketBase, nbuk, E);
  k_place<<<NBLK, 256, 0, stream>>>(ept, E, offs, ebuk, nbuk);
  k_bsort2<<<nbuk, 256, 0, stream>>>(ebuk, bucketBase, rp, dinv, csrc, N);

  // x conversion + stats, W prep (fused)
  int n4 = N * DD / 4;
  k_cvtw<<<1024 + 128, 256, 0, stream>>>((const float4*)x, (ushort4*)xb, n4, part, W1, W2, wimg);

  int gb = (N + 127) / 128;
  int ab = 8 * ((N + 31) / 32);  // 8 column-slices x node blocks
  k_gemm<<<gb, 256, 0, stream>>>(xb, wimg, dinv, h, N);
  k_agg<<<ab, 256, 0, stream>>>(h, dinv, b1, rp, csrc, y1, N, part, 128);
  k_gemm<<<gb, 256, 0, stream>>>(y1, wimg + 16384, dinv, h, N);
  k_agg<<<ab, 256, 0, stream>>>(h, dinv, b2, rp, csrc, y2, N, part, 256);

  k_fold_a<<<1, 384, 0, stream>>>(part, gamma, beta, Wo, bo, aS, boP, N);
  k_foldw<<<192, 256, 0, stream>>>(aS, Wo, wopimg);
  k_gemm_out<<<gb, 256, 0, stream>>>(xb, y1, y2, wopimg, boP, out, N);
}

// Round 9
// 330.282 us; speedup vs baseline: 1.7034x; 1.7034x over previous
//
#include <hip/hip_runtime.h>
#include <hip/hip_bf16.h>

#define DD 128
#define NBLK 256     // blocks for hist/place passes
#define MAXBUK 1024  // max dst-buckets (256 nodes each)
#define CAP2 12288   // max edges per bucket for LDS sort staging

typedef __attribute__((ext_vector_type(8))) short bf16x8;
typedef __attribute__((ext_vector_type(4))) float f32x4;
typedef unsigned int uint32;

__device__ __forceinline__ unsigned short f2b(float f) {
  __hip_bfloat16 h = __float2bfloat16(f);
  unsigned short u;
  __builtin_memcpy(&u, &h, 2);
  return u;
}
__device__ __forceinline__ float b2f_lo(uint32 v) { return __uint_as_float(v << 16); }
__device__ __forceinline__ float b2f_hi(uint32 v) { return __uint_as_float(v & 0xffff0000u); }

__device__ __forceinline__ void acc8(float* acc, uint4 h, float w) {
  acc[0] = fmaf(w, b2f_lo(h.x), acc[0]);
  acc[1] = fmaf(w, b2f_hi(h.x), acc[1]);
  acc[2] = fmaf(w, b2f_lo(h.y), acc[2]);
  acc[3] = fmaf(w, b2f_hi(h.y), acc[3]);
  acc[4] = fmaf(w, b2f_lo(h.z), acc[4]);
  acc[5] = fmaf(w, b2f_hi(h.z), acc[5]);
  acc[6] = fmaf(w, b2f_lo(h.w), acc[6]);
  acc[7] = fmaf(w, b2f_hi(h.w), acc[7]);
}

// per-block int64-vs-int32 detection: hi-words of first 64 src entries all zero <=> int64
__device__ __forceinline__ bool detect_i64(const int* e, int E) {
  int lane = threadIdx.x & 63;
  int samples = E < 64 ? E : 64;
  int v = (lane < samples) ? e[2 * lane + 1] : 0;
  return __ballot(v != 0) == 0ULL;
}

// ---------------- per-block bucket histogram ----------------
__global__ __launch_bounds__(256) void k_hist(const void* __restrict__ eptr, int E,
                                              int* __restrict__ histT, int nbuk) {
  __shared__ int hist[MAXBUK];
  int t = threadIdx.x, blk = blockIdx.x;
  bool f = detect_i64((const int*)eptr, E);
  for (int b = t; b < nbuk; b += 256) hist[b] = 0;
  __syncthreads();
  int chunk = (E + NBLK - 1) / NBLK;
  int i0 = blk * chunk, i1 = min(E, i0 + chunk);
  for (int i = i0 + t; i < i1; i += 256) {
    int dst = f ? (int)((const long long*)eptr)[E + i] : ((const int*)eptr)[E + i];
    atomicAdd(&hist[dst >> 8], 1);
  }
  __syncthreads();
  for (int b = t; b < nbuk; b += 256) histT[b * NBLK + blk] = hist[b];
}

// ---------------- single-block: bucket totals, bucket base scan, per-block offsets ----------------
__global__ __launch_bounds__(1024) void k_bktscan(const int* __restrict__ histT,
                                                  int* __restrict__ offs,
                                                  int* __restrict__ bucketBase,
                                                  int nbuk, int E) {
  __shared__ int tot[MAXBUK];
  int t = threadIdx.x, lane = t & 63, wv = t >> 6;  // 16 waves
  for (int b = t; b < MAXBUK; b += 1024) tot[b] = 0;
  __syncthreads();
  for (int b = wv; b < nbuk; b += 16) {
    const int4 vv = *(const int4*)(histT + b * NBLK + lane * 4);
    int lsum = vv.x + vv.y + vv.z + vv.w;
    int s = lsum;
#pragma unroll
    for (int o = 1; o < 64; o <<= 1) {
      int u = __shfl_up(s, o);
      if (lane >= o) s += u;
    }
    if (lane == 63) tot[b] = s;
  }
  __syncthreads();
  for (int o = 1; o < MAXBUK; o <<= 1) {
    int u = (t >= o) ? tot[t - o] : 0;
    __syncthreads();
    tot[t] += u;
    __syncthreads();
  }
  for (int b = wv; b < nbuk; b += 16) {
    int idx = b * NBLK + lane * 4;
    const int4 vv = *(const int4*)(histT + idx);
    int lsum = vv.x + vv.y + vv.z + vv.w;
    int s = lsum;
#pragma unroll
    for (int o = 1; o < 64; o <<= 1) {
      int u = __shfl_up(s, o);
      if (lane >= o) s += u;
    }
    int tb = __shfl(s, 63);
    int bbase = tot[b] - tb;
    int excl = bbase + s - lsum;
    offs[idx] = excl;
    offs[idx + 1] = excl + vv.x;
    offs[idx + 2] = excl + vv.x + vv.y;
    offs[idx + 3] = excl + vv.x + vv.y + vv.z;
    if (lane == 0) bucketBase[b] = bbase;
  }
  if (t == 0) bucketBase[nbuk] = E;
}

// ---------------- place edges into bucket regions (block-contiguous runs) ----------------
__global__ __launch_bounds__(256) void k_place(const void* __restrict__ eptr, int E,
                                               const int* __restrict__ offs,
                                               int* __restrict__ ebuk, int nbuk) {
  __shared__ int cur[MAXBUK];
  int t = threadIdx.x, blk = blockIdx.x;
  bool f = detect_i64((const int*)eptr, E);
  for (int b = t; b < nbuk; b += 256) cur[b] = offs[b * NBLK + blk];
  __syncthreads();
  int chunk = (E + NBLK - 1) / NBLK;
  int i0 = blk * chunk, i1 = min(E, i0 + chunk);
  for (int i = i0 + t; i < i1; i += 256) {
    int src, dst;
    if (f) {
      src = (int)((const long long*)eptr)[i];
      dst = (int)((const long long*)eptr)[E + i];
    } else {
      src = ((const int*)eptr)[i];
      dst = ((const int*)eptr)[E + i];
    }
    int pos = atomicAdd(&cur[dst >> 8], 1);
    ebuk[pos] = (src << 8) | (dst & 255);
  }
}

// ---------------- per-bucket: degree count -> rp + dinv + LDS counting sort -> csrc ----------------
__global__ __launch_bounds__(256) void k_bsort2(const int* __restrict__ ebuk,
                                                const int* __restrict__ bucketBase,
                                                int* __restrict__ rp, float* __restrict__ dinv,
                                                int* __restrict__ csrc, int n) {
  __shared__ int cnt[256];
  __shared__ int wss[4];
  __shared__ int outb[CAP2];
  int b = blockIdx.x, t = threadIdx.x, lane = t & 63, wv = t >> 6;
  int v0 = b << 8;
  int v1 = min(v0 + 256, n);
  int nn = v1 - v0;
  int base = bucketBase[b];
  int total = bucketBase[b + 1] - base;
  cnt[t] = 0;
  __syncthreads();
  for (int i = t; i < total; i += 256) atomicAdd(&cnt[ebuk[base + i] & 255], 1);
  __syncthreads();
  int v = cnt[t];
  int incl = v;
#pragma unroll
  for (int o = 1; o < 64; o <<= 1) {
    int u = __shfl_up(incl, o);
    if (lane >= o) incl += u;
  }
  if (lane == 63) wss[wv] = incl;
  __syncthreads();
  int woff = 0;
  for (int k = 0; k < wv; ++k) woff += wss[k];
  int excl = woff + incl - v;
  if (t < nn) {
    rp[v0 + t] = base + excl;
    dinv[v0 + t] = rsqrtf((float)v + 1.0f);
  }
  if (t == 255) rp[v1] = base + excl + v;
  __syncthreads();
  cnt[t] = excl;
  __syncthreads();
  if (total <= CAP2) {
    for (int i = t; i < total; i += 256) {
      int e = ebuk[base + i];
      int slot = atomicAdd(&cnt[e & 255], 1);
      outb[slot] = e >> 8;
    }
    __syncthreads();
    for (int i = t; i < total; i += 256) csrc[base + i] = outb[i];
  } else {
    for (int i = t; i < total; i += 256) {
      int e = ebuk[base + i];
      int slot = atomicAdd(&cnt[e & 255], 1);
      csrc[base + slot] = e >> 8;
    }
  }
}

// ---------------- fused: x -> bf16 + column stats (blocks 0..1023), W prep (1024..1151) ----------------
__global__ __launch_bounds__(256) void k_cvtw(const float4* __restrict__ x,
                                              ushort4* __restrict__ xb, int n4,
                                              float* __restrict__ part,
                                              const float* __restrict__ W1,
                                              const float* __restrict__ W2,
                                              unsigned short* __restrict__ wimg) {
  __shared__ float sh[256][8];
  int t = threadIdx.x;
  int bid = blockIdx.x;
  if (bid >= 1024) {
    int i = (bid - 1024) * 256 + t;  // 0..32767
    if (i < 32768) {
      int wsel = i >> 14;
      int j = i & 16383;
      int k = j >> 7, col = j & 127;
      float v = (wsel ? W2 : W1)[j];
      int chunk = (k >> 3) ^ (col & 7);
      wimg[wsel * 16384 + col * 128 + chunk * 8 + (k & 7)] = f2b(v);
    }
    return;
  }
  float s[4] = {0, 0, 0, 0}, q[4] = {0, 0, 0, 0};
  for (int i = bid * 256 + t; i < n4; i += 1024 * 256) {
    float4 a = x[i];
    ushort4 o;
    o.x = f2b(a.x); o.y = f2b(a.y); o.z = f2b(a.z); o.w = f2b(a.w);
    xb[i] = o;
    s[0] += a.x; s[1] += a.y; s[2] += a.z; s[3] += a.w;
    q[0] = fmaf(a.x, a.x, q[0]); q[1] = fmaf(a.y, a.y, q[1]);
    q[2] = fmaf(a.z, a.z, q[2]); q[3] = fmaf(a.w, a.w, q[3]);
  }
#pragma unroll
  for (int j = 0; j < 4; ++j) { sh[t][j] = s[j]; sh[t][4 + j] = q[j]; }
  __syncthreads();
  if (t < 32) {
#pragma unroll
    for (int g = 1; g < 8; ++g)
#pragma unroll
      for (int j = 0; j < 4; ++j) {
        s[j] += sh[g * 32 + t][j];
        q[j] += sh[g * 32 + t][4 + j];
      }
    float* pp = part + (size_t)(bid & 63) * 768;
#pragma unroll
    for (int j = 0; j < 4; ++j) {
      atomicAdd(&pp[(t * 4 + j) * 2], s[j]);
      atomicAdd(&pp[(t * 4 + j) * 2 + 1], q[j]);
    }
  }
}

// ---------------- MFMA GEMM: H = bf16((A @ W) * dinv[row]) ----------------
__global__ __launch_bounds__(256) void k_gemm(const unsigned short* __restrict__ Ab,
                                              const unsigned short* __restrict__ Wimg,
                                              const float* __restrict__ dinv,
                                              unsigned short* __restrict__ H, int n) {
  __shared__ __align__(16) unsigned short Wl[16384];
  int t = threadIdx.x, lane = t & 63, w = t >> 6;
#pragma unroll
  for (int i = t; i < 2048; i += 256) ((int4*)Wl)[i] = ((const int4*)Wimg)[i];
  __syncthreads();
  int rowBase = blockIdx.x * 128 + w * 32;
  int r16 = lane & 15, half = lane >> 4;
  f32x4 acc[2][8];
#pragma unroll
  for (int m = 0; m < 2; ++m)
#pragma unroll
    for (int nn = 0; nn < 8; ++nn) acc[m][nn] = (f32x4){0.f, 0.f, 0.f, 0.f};
#pragma unroll
  for (int ks = 0; ks < 4; ++ks) {
    bf16x8 a[2];
#pragma unroll
    for (int m = 0; m < 2; ++m) {
      int r = rowBase + m * 16 + r16;
      if (r >= n) r = n - 1;
      a[m] = *(const bf16x8*)(Ab + (size_t)r * DD + ks * 32 + half * 8);
    }
#pragma unroll
    for (int nn = 0; nn < 8; ++nn) {
      int col = nn * 16 + r16;
      int chunk = (ks * 4 + half) ^ (col & 7);
      bf16x8 b = *(const bf16x8*)(Wl + col * 128 + chunk * 8);
      acc[0][nn] = __builtin_amdgcn_mfma_f32_16x16x32_bf16(a[0], b, acc[0][nn], 0, 0, 0);
      acc[1][nn] = __builtin_amdgcn_mfma_f32_16x16x32_bf16(a[1], b, acc[1][nn], 0, 0, 0);
    }
  }
#pragma unroll
  for (int m = 0; m < 2; ++m) {
    int rb = rowBase + m * 16 + half * 4;
    float dv[4];
#pragma unroll
    for (int i = 0; i < 4; ++i) dv[i] = (rb + i < n) ? dinv[rb + i] : 0.f;
#pragma unroll
    for (int nn = 0; nn < 8; ++nn) {
      int col = nn * 16 + r16;
#pragma unroll
      for (int i = 0; i < 4; ++i) {
        int r = rb + i;
        if (r < n) H[(size_t)r * DD + col] = f2b(acc[m][nn][i] * dv[i]);
      }
    }
  }
}

// ---------------- aggregation: 4 nodes/wave, 16 gather loads in flight + fused stats ----------------
__global__ __launch_bounds__(256) void k_agg(const unsigned short* __restrict__ hs,
                                             const float* __restrict__ dinv,
                                             const float* __restrict__ b,
                                             const int* __restrict__ rp,
                                             const int* __restrict__ csrc,
                                             unsigned short* __restrict__ y, int n,
                                             float* __restrict__ part, int cb) {
  __shared__ float sh_s[4][128];
  __shared__ float sh_q[4][128];
  int wid = threadIdx.x >> 6, lane = threadIdx.x & 63;
  int eidx = lane >> 4;  // 0..3: edge group
  int seg = lane & 15;   // 0..15: 16B segment of the row
  int v0 = blockIdx.x * 16 + wid * 4;  // 4 waves x 4 nodes
  int vv[4] = {v0, v0 + 1, v0 + 2, v0 + 3};
  bool ok[4];
  int lo[4], hi[4];
#pragma unroll
  for (int m = 0; m < 4; ++m) {
    ok[m] = vv[m] < n;
    lo[m] = ok[m] ? rp[vv[m]] : 0;
    hi[m] = ok[m] ? rp[vv[m] + 1] : 0;
  }
  const uint4* H4 = (const uint4*)hs;  // one row = 16 uint4
  float acc[4][8];
#pragma unroll
  for (int m = 0; m < 4; ++m)
#pragma unroll
    for (int j = 0; j < 8; ++j) acc[m][j] = 0.f;
  int eb[4] = {lo[0], lo[1], lo[2], lo[3]};
  while (eb[0] < hi[0] || eb[1] < hi[1] || eb[2] < hi[2] || eb[3] < hi[3]) {
    int ec[4], ul[4];
    int iters = 0;
#pragma unroll
    for (int m = 0; m < 4; ++m) {
      int e = hi[m] - eb[m];
      ec[m] = e < 0 ? 0 : (e > 64 ? 64 : e);
      ul[m] = (eb[m] + lane < hi[m]) ? csrc[eb[m] + lane] : 0;
      iters = iters > ec[m] ? iters : ec[m];
    }
    for (int cc = 0; cc < iters; cc += 16) {
      int u[4][4];
      float wt[4][4];
#pragma unroll
      for (int m = 0; m < 4; ++m) {
        u[m][0] = __shfl(ul[m], cc + eidx);
        u[m][1] = __shfl(ul[m], cc + 4 + eidx);
        u[m][2] = __shfl(ul[m], cc + 8 + eidx);
        u[m][3] = __shfl(ul[m], cc + 12 + eidx);
        wt[m][0] = (cc + eidx < ec[m]) ? 1.f : 0.f;
        wt[m][1] = (cc + 4 + eidx < ec[m]) ? 1.f : 0.f;
        wt[m][2] = (cc + 8 + eidx < ec[m]) ? 1.f : 0.f;
        wt[m][3] = (cc + 12 + eidx < ec[m]) ? 1.f : 0.f;
      }
      uint4 hv[4][4];
#pragma unroll
      for (int m = 0; m < 4; ++m)
#pragma unroll
        for (int k = 0; k < 4; ++k)
          hv[m][k] = H4[(size_t)u[m][k] * 16 + seg];
#pragma unroll
      for (int m = 0; m < 4; ++m)
#pragma unroll
        for (int k = 0; k < 4; ++k)
          acc8(acc[m], hv[m][k], wt[m][k]);
    }
#pragma unroll
    for (int m = 0; m < 4; ++m) eb[m] += 64;
  }
  // butterfly-reduce across the 4 edge-groups (lane bits 4,5)
#pragma unroll
  for (int m = 0; m < 4; ++m)
#pragma unroll
    for (int j = 0; j < 8; ++j) {
      acc[m][j] += __shfl_xor(acc[m][j], 16);
      acc[m][j] += __shfl_xor(acc[m][j], 32);
    }
  float4 bb0 = ((const float4*)b)[seg * 2];
  float4 bb1 = ((const float4*)b)[seg * 2 + 1];
  float bv[8] = {bb0.x, bb0.y, bb0.z, bb0.w, bb1.x, bb1.y, bb1.z, bb1.w};
  float st_s[8], st_q[8];
#pragma unroll
  for (int j = 0; j < 8; ++j) { st_s[j] = 0.f; st_q[j] = 0.f; }
#pragma unroll
  for (int m = 0; m < 4; ++m) {
    float o[8];
    if (ok[m]) {
      uint4 sfv = H4[(size_t)vv[m] * 16 + seg];
      float sf[8] = {b2f_lo(sfv.x), b2f_hi(sfv.x), b2f_lo(sfv.y), b2f_hi(sfv.y),
                     b2f_lo(sfv.z), b2f_hi(sfv.z), b2f_lo(sfv.w), b2f_hi(sfv.w)};
      float dv = dinv[vv[m]];
#pragma unroll
      for (int j = 0; j < 8; ++j) o[j] = fmaxf(fmaf(dv, acc[m][j] + sf[j], bv[j]), 0.f);
      if (eidx == 0) {
        uint4 ov;
        ov.x = (uint32)f2b(o[0]) | ((uint32)f2b(o[1]) << 16);
        ov.y = (uint32)f2b(o[2]) | ((uint32)f2b(o[3]) << 16);
        ov.z = (uint32)f2b(o[4]) | ((uint32)f2b(o[5]) << 16);
        ov.w = (uint32)f2b(o[6]) | ((uint32)f2b(o[7]) << 16);
        ((uint4*)y)[(size_t)vv[m] * 16 + seg] = ov;
      }
    } else {
#pragma unroll
      for (int j = 0; j < 8; ++j) o[j] = 0.f;
    }
#pragma unroll
    for (int j = 0; j < 8; ++j) {
      st_s[j] += o[j];
      st_q[j] = fmaf(o[j], o[j], st_q[j]);
    }
  }
  if (eidx == 0) {
#pragma unroll
    for (int j = 0; j < 8; ++j) {
      sh_s[wid][seg * 8 + j] = st_s[j];
      sh_q[wid][seg * 8 + j] = st_q[j];
    }
  }
  __syncthreads();
  if (threadIdx.x < 128) {
    int c = threadIdx.x;
    float s = sh_s[0][c] + sh_s[1][c] + sh_s[2][c] + sh_s[3][c];
    float q = sh_q[0][c] + sh_q[1][c] + sh_q[2][c] + sh_q[3][c];
    float* pp = part + (size_t)(blockIdx.x & 63) * 768;
    atomicAdd(&pp[(cb + c) * 2], s);
    atomicAdd(&pp[(cb + c) * 2 + 1], q);
  }
}

// ---------------- BN fold: reduce partials, compute scale/shift + folded bias ----------------
__global__ void k_fold_a(const float* __restrict__ part, const float* __restrict__ gamma,
                         const float* __restrict__ beta, const float* __restrict__ Wo,
                         const float* __restrict__ bo, float* __restrict__ aS,
                         float* __restrict__ boP, int n) {
  __shared__ float cSh[384];
  int t = threadIdx.x;  // 0..383
  float s = 0.f, q = 0.f;
  for (int r = 0; r < 64; ++r) {
    s += part[r * 768 + t * 2];
    q += part[r * 768 + t * 2 + 1];
  }
  float inv_n = 1.0f / (float)n;
  float mu = s * inv_n;
  float var = q * inv_n - mu * mu;
  float a = gamma[t] * rsqrtf(var + 1e-5f);
  aS[t] = a;
  cSh[t] = beta[t] - mu * a;
  __syncthreads();
  if (t < DD) {
    float sb = bo[t];
    for (int k = 0; k < 384; ++k) sb = fmaf(cSh[k], Wo[k * DD + t], sb);
    boP[t] = sb;
  }
}

// ---------------- WoP image (bf16, pre-swizzled) ----------------
__global__ void k_foldw(const float* __restrict__ aS, const float* __restrict__ Wo,
                        unsigned short* __restrict__ wopimg) {
  int i = blockIdx.x * 256 + threadIdx.x;  // 0..49151
  if (i >= 49152) return;
  int krow = i >> 7, col = i & 127;
  float v = aS[krow] * Wo[i];
  int p = krow >> 7, kk = krow & 127;
  int chunk = (kk >> 3) ^ (col & 7);
  wopimg[p * 16384 + col * 128 + chunk * 8 + (kk & 7)] = f2b(v);
}

// ---------------- final MFMA GEMM: out = [xb|y1|y2] @ WoP + boP (f32 out) ----------------
__global__ __launch_bounds__(256) void k_gemm_out(const unsigned short* __restrict__ xb,
                                                  const unsigned short* __restrict__ y1,
                                                  const unsigned short* __restrict__ y2,
                                                  const unsigned short* __restrict__ Wimg3,
                                                  const float* __restrict__ boP,
                                                  float* __restrict__ out, int n) {
  __shared__ __align__(16) unsigned short Wl[16384];
  int t = threadIdx.x, lane = t & 63, w = t >> 6;
  int rowBase = blockIdx.x * 128 + w * 32;
  int r16 = lane & 15, half = lane >> 4;
  f32x4 acc[2][8];
#pragma unroll
  for (int m = 0; m < 2; ++m)
#pragma unroll
    for (int nn = 0; nn < 8; ++nn) acc[m][nn] = (f32x4){0.f, 0.f, 0.f, 0.f};
  for (int p = 0; p < 3; ++p) {
    const unsigned short* Ab = (p == 0) ? xb : (p == 1) ? y1 : y2;
    __syncthreads();
#pragma unroll
    for (int i = t; i < 2048; i += 256) ((int4*)Wl)[i] = ((const int4*)(Wimg3 + p * 16384))[i];
    __syncthreads();
#pragma unroll
    for (int ks = 0; ks < 4; ++ks) {
      bf16x8 a[2];
#pragma unroll
      for (int m = 0; m < 2; ++m) {
        int r = rowBase + m * 16 + r16;
        if (r >= n) r = n - 1;
        a[m] = *(const bf16x8*)(Ab + (size_t)r * DD + ks * 32 + half * 8);
      }
#pragma unroll
      for (int nn = 0; nn < 8; ++nn) {
        int col = nn * 16 + r16;
        int chunk = (ks * 4 + half) ^ (col & 7);
        bf16x8 b = *(const bf16x8*)(Wl + col * 128 + chunk * 8);
        acc[0][nn] = __builtin_amdgcn_mfma_f32_16x16x32_bf16(a[0], b, acc[0][nn], 0, 0, 0);
        acc[1][nn] = __builtin_amdgcn_mfma_f32_16x16x32_bf16(a[1], b, acc[1][nn], 0, 0, 0);
      }
    }
  }
#pragma unroll
  for (int m = 0; m < 2; ++m) {
    int rb = rowBase + m * 16 + half * 4;
#pragma unroll
    for (int nn = 0; nn < 8; ++nn) {
      int col = nn * 16 + r16;
      float bb = boP[col];
#pragma unroll
      for (int i = 0; i < 4; ++i) {
        int r = rb + i;
        if (r < n) out[(size_t)r * DD + col] = acc[m][nn][i] + bb;
      }
    }
  }
}

extern "C" void kernel_launch(void* const* d_in, const int* in_sizes, int n_in,
                              void* d_out, int out_size, void* d_ws, size_t ws_size,
                              hipStream_t stream) {
  const float* x = (const float*)d_in[0];
  const void* ept = d_in[1];
  const float* W1 = (const float*)d_in[2];
  const float* b1 = (const float*)d_in[3];
  const float* W2 = (const float*)d_in[4];
  const float* b2 = (const float*)d_in[5];
  const float* gamma = (const float*)d_in[6];
  const float* beta = (const float*)d_in[7];
  const float* Wo = (const float*)d_in[8];
  const float* bo = (const float*)d_in[9];
  float* out = (float*)d_out;
  int N = in_sizes[0] / DD;
  int E = in_sizes[1] / 2;
  int nbuk = (N + 255) >> 8;  // must be <= MAXBUK (N <= 262144)

  char* w = (char*)d_ws;
  size_t off = 0;
  auto alloc = [&](size_t bytes) {
    void* p = w + off;
    off = (off + bytes + 255) & ~(size_t)255;
    return p;
  };
  float* dinv = (float*)alloc((size_t)N * 4);
  int* rp = (int*)alloc((size_t)(N + 1) * 4);
  int* csrc = (int*)alloc((size_t)E * 4);
  int* ebuk = (int*)alloc((size_t)E * 4);
  int* histT = (int*)alloc((size_t)MAXBUK * NBLK * 4);
  int* offs = (int*)alloc((size_t)MAXBUK * NBLK * 4);
  int* bucketBase = (int*)alloc((size_t)(MAXBUK + 1) * 4);
  unsigned short* xb = (unsigned short*)alloc((size_t)N * DD * 2);
  unsigned short* h = (unsigned short*)alloc((size_t)N * DD * 2);
  unsigned short* y1 = (unsigned short*)alloc((size_t)N * DD * 2);
  unsigned short* y2 = (unsigned short*)alloc((size_t)N * DD * 2);
  unsigned short* wimg = (unsigned short*)alloc(32768 * 2);
  unsigned short* wopimg = (unsigned short*)alloc(49152 * 2);
  float* part = (float*)alloc((size_t)64 * 768 * 4);
  float* aS = (float*)alloc(384 * 4);
  float* boP = (float*)alloc(DD * 4);

  hipMemsetAsync(part, 0, (size_t)64 * 768 * 4, stream);

  // CSR construction (atomic-free, bucketized)
  k_hist<<<NBLK, 256, 0, stream>>>(ept, E, histT, nbuk);
  k_bktscan<<<1, 1024, 0, stream>>>(histT, offs, bucketBase, nbuk, E);
  k_place<<<NBLK, 256, 0, stream>>>(ept, E, offs, ebuk, nbuk);
  k_bsort2<<<nbuk, 256, 0, stream>>>(ebuk, bucketBase, rp, dinv, csrc, N);

  // x conversion + stats, W prep (fused)
  int n4 = N * DD / 4;
  k_cvtw<<<1024 + 128, 256, 0, stream>>>((const float4*)x, (ushort4*)xb, n4, part, W1, W2, wimg);

  int gb = (N + 127) / 128;
  int ab = (N + 15) / 16;
  k_gemm<<<gb, 256, 0, stream>>>(xb, wimg, dinv, h, N);
  k_agg<<<ab, 256, 0, stream>>>(h, dinv, b1, rp, csrc, y1, N, part, 128);
  k_gemm<<<gb, 256, 0, stream>>>(y1, wimg + 16384, dinv, h, N);
  k_agg<<<ab, 256, 0, stream>>>(h, dinv, b2, rp, csrc, y2, N, part, 256);

  k_fold_a<<<1, 384, 0, stream>>>(part, gamma, beta, Wo, bo, aS, boP, N);
  k_foldw<<<192, 256, 0, stream>>>(aS, Wo, wopimg);
  k_gemm_out<<<gb, 256, 0, stream>>>(xb, y1, y2, wopimg, boP, out, N);
}